// Round 3
// baseline (296.214 us; speedup 1.0000x reference)
//
#include <hip/hip_runtime.h>
#include <math.h>

#define BATCH 16
#define CIN 4
#define LEN 300000
#define KW 11
#define LC (LEN - KW + 1)   // 299990
#define LCP 300000          // padded row stride for ch workspace
#define LEAK 1e-4f
#define EPS_N 1e-12f

#define TPB 256
#define EPT 16                       // elements per thread
#define BPB (TPB * EPT)              // 4096 elements per block
#define NBX ((LC + BPB - 1) / BPB)   // 74
#define NBLK (NBX * BATCH)           // 1184

// ws layout (tickets zeroed by one small memsetAsync; all else written-before-read):
//   ticket  unsigned[2]        @ 0
//   absP    double[NBLK]       @ 1024   (9472 B)
//   maxP    float [NBLK]       @ 10752  (4736 B)
//   stats   float [32]         @ 15616  {denom,max} per b
//   sP      double[NBLK*3]     @ 16384  (28416 B)
//   ch      float [BATCH*LCP]  @ 65536  (19.2 MB)

__global__ __launch_bounds__(256) void conv_stats(
    const float* __restrict__ data, const float* __restrict__ W,
    const float* __restrict__ bias, const int* __restrict__ aidx,
    float* __restrict__ ch, double* __restrict__ absP, float* __restrict__ maxP,
    float* __restrict__ stats, unsigned* __restrict__ ticket)
{
    const int b = blockIdx.y, j = blockIdx.x, tid = threadIdx.x;
    const int a = __builtin_amdgcn_readfirstlane(aidx[0]);

    float w[CIN * KW];
#pragma unroll
    for (int k = 0; k < CIN * KW; ++k) w[k] = W[a * CIN * KW + k];
    const float sb = bias[a];

    const float* dbase = data + (size_t)b * (CIN * (size_t)LEN);
    float* chrow = ch + (size_t)b * LCP;
    const int o = j * BPB + tid * EPT;

    float aabs = 0.0f, amax = -INFINITY;

    if (o + EPT <= LC) {
        // fast path: max o = 299968 -> highest load index o+27 = 299995 < LEN, in-bounds
        float acc[EPT];
#pragma unroll
        for (int u = 0; u < EPT; ++u) acc[u] = sb;
#pragma unroll
        for (int c = 0; c < CIN; ++c) {
            const float* src = dbase + (size_t)c * LEN + o;
            float x[28];
#pragma unroll
            for (int i = 0; i < 7; ++i) {
                const float4 v = *(const float4*)(src + 4 * i);
                x[4 * i] = v.x; x[4 * i + 1] = v.y;
                x[4 * i + 2] = v.z; x[4 * i + 3] = v.w;
            }
#pragma unroll
            for (int u = 0; u < EPT; ++u)
#pragma unroll
                for (int k = 0; k < KW; ++k)
                    acc[u] = fmaf(x[u + k], w[c * KW + k], acc[u]);
        }
#pragma unroll
        for (int u = 0; u < EPT; ++u) {
            const float y = acc[u] > 0.0f ? acc[u] : LEAK * acc[u];
            acc[u] = y;
            aabs += fabsf(y);
            amax = fmaxf(amax, y);
        }
#pragma unroll
        for (int i = 0; i < 4; ++i)
            *(float4*)(chrow + o + 4 * i) =
                make_float4(acc[4 * i], acc[4 * i + 1], acc[4 * i + 2], acc[4 * i + 3]);
    } else {
        for (int l = o; l < LC; ++l) {
            float accv = sb;
#pragma unroll
            for (int c = 0; c < CIN; ++c)
#pragma unroll
                for (int k = 0; k < KW; ++k)
                    accv = fmaf(dbase[(size_t)c * LEN + l + k], w[c * KW + k], accv);
            const float y = accv > 0.0f ? accv : LEAK * accv;
            chrow[l] = y;
            aabs += fabsf(y);
            amax = fmaxf(amax, y);
        }
    }

#pragma unroll
    for (int off = 32; off; off >>= 1) {
        aabs += __shfl_down(aabs, off);
        amax = fmaxf(amax, __shfl_down(amax, off));
    }
    __shared__ float ra[4], rm[4];
    __shared__ bool last;
    const int wv = tid >> 6;
    if ((tid & 63) == 0) { ra[wv] = aabs; rm[wv] = amax; }
    __syncthreads();
    if (tid == 0) {
        absP[b * NBX + j] = (double)((ra[0] + ra[1]) + (ra[2] + ra[3]));
        maxP[b * NBX + j] = fmaxf(fmaxf(rm[0], rm[1]), fmaxf(rm[2], rm[3]));
        __threadfence();
        last = (atomicAdd(ticket, 1u) == NBLK - 1);
    }
    __syncthreads();
    if (last) {
        __threadfence();   // invalidate L1 so partials from other XCDs are seen
        const int wave = tid >> 6, lane = tid & 63;
        for (int bb = wave; bb < BATCH; bb += 4) {
            double s = 0.0; float m = -INFINITY;
            for (int i = lane; i < NBX; i += 64) {
                s += absP[bb * NBX + i];
                m = fmaxf(m, maxP[bb * NBX + i]);
            }
#pragma unroll
            for (int off = 32; off; off >>= 1) {
                s += __shfl_down(s, off);
                m = fmaxf(m, __shfl_down(m, off));
            }
            if (lane == 0) {
                stats[2 * bb]     = fmaxf((float)s, EPS_N);
                stats[2 * bb + 1] = m;
            }
        }
    }
}

__global__ __launch_bounds__(256) void softmax_pass(
    const float* __restrict__ ch, const float* __restrict__ stats,
    float* __restrict__ chan_out, double* __restrict__ sP,
    float* __restrict__ out, unsigned* __restrict__ ticket)
{
    const int b = blockIdx.y, j = blockIdx.x, tid = threadIdx.x;
    const float inv = 1.0f / stats[2 * b];
    const float mx  = stats[2 * b + 1] * inv;

    const float* src = ch + (size_t)b * LCP;
    float* dst = chan_out + (size_t)b * LC;   // base offset 32+b*299990: mod4 = 2b&3
    const int o = j * BPB + tid * EPT;

    double te = 0.0, t1 = 0.0, t2 = 0.0;

    if (o + EPT <= LC) {
        float cc[EPT];
#pragma unroll
        for (int i = 0; i < 4; ++i) {
            const float4 v = *(const float4*)(src + o + 4 * i);
            cc[4 * i] = v.x * inv; cc[4 * i + 1] = v.y * inv;
            cc[4 * i + 2] = v.z * inv; cc[4 * i + 3] = v.w * inv;
        }
        if ((b & 1) == 0) {
#pragma unroll
            for (int i = 0; i < 4; ++i)
                *(float4*)(dst + o + 4 * i) =
                    make_float4(cc[4 * i], cc[4 * i + 1], cc[4 * i + 2], cc[4 * i + 3]);
        } else {  // row base only 8B-aligned
#pragma unroll
            for (int i = 0; i < 8; ++i)
                *(float2*)(dst + o + 2 * i) = make_float2(cc[2 * i], cc[2 * i + 1]);
        }
        float se = 0.0f, su = 0.0f, suu = 0.0f;
#pragma unroll
        for (int u = 0; u < EPT; ++u) {
            const float e = expf(cc[u] - mx);
            se += e;
            su += e * (float)u;
            suu += e * (float)(u * u);
        }
        const double od = (double)o;
        te = (double)se;
        t1 = od * (double)se + (double)su;
        t2 = od * od * (double)se + 2.0 * od * (double)su + (double)suu;
    } else {
        for (int l = o; l < LC; ++l) {
            const float c = src[l] * inv;
            dst[l] = c;
            const float e = expf(c - mx);
            const double xd = (double)l;
            te += (double)e;
            t1 += (double)e * xd;
            t2 += (double)e * xd * xd;
        }
    }

#pragma unroll
    for (int off = 32; off; off >>= 1) {
        te += __shfl_down(te, off);
        t1 += __shfl_down(t1, off);
        t2 += __shfl_down(t2, off);
    }
    __shared__ double we[4], w1[4], w2[4];
    __shared__ bool last;
    const int wv = tid >> 6;
    if ((tid & 63) == 0) { we[wv] = te; w1[wv] = t1; w2[wv] = t2; }
    __syncthreads();
    if (tid == 0) {
        double* p = sP + (size_t)(b * NBX + j) * 3;
        p[0] = (we[0] + we[1]) + (we[2] + we[3]);
        p[1] = (w1[0] + w1[1]) + (w1[2] + w1[3]);
        p[2] = (w2[0] + w2[1]) + (w2[2] + w2[3]);
        __threadfence();
        last = (atomicAdd(ticket, 1u) == NBLK - 1);
    }
    __syncthreads();
    if (last) {
        __threadfence();
        const int wave = tid >> 6, lane = tid & 63;
        for (int bb = wave; bb < BATCH; bb += 4) {
            double e = 0.0, m1 = 0.0, m2 = 0.0;
            for (int i = lane; i < NBX; i += 64) {
                const double* p = sP + (size_t)(bb * NBX + i) * 3;
                e += p[0]; m1 += p[1]; m2 += p[2];
            }
#pragma unroll
            for (int off = 32; off; off >>= 1) {
                e  += __shfl_down(e, off);
                m1 += __shfl_down(m1, off);
                m2 += __shfl_down(m2, off);
            }
            if (lane == 0) {
                const double mean = m1 / e;
                const double var  = m2 / e - mean * mean;

                const double n   = (double)LC;
                const double nm1 = n - 1.0;
                const double S1p = 0.5 * n * nm1;
                const double S2p = nm1 * n * (2.0 * n - 1.0) / 6.0;
                const double S3p = S1p * S1p;
                const double S4p = S2p * (3.0 * n * n - 3.0 * n - 1.0) / 5.0;

                const double mu  = mean;
                const double mu2 = mu * mu;
                const double P3 = S3p - 3.0 * mu * S2p + 3.0 * mu2 * S1p - n * mu * mu2;
                const double P4 = S4p - 4.0 * mu * S3p + 6.0 * mu2 * S2p
                                  - 4.0 * mu * mu2 * S1p + n * mu2 * mu2;

                const double sv = sqrt(var);
                out[bb]         = (float)(P3 / (n * sv * sv * sv));
                out[BATCH + bb] = (float)(P4 / (n * var * var) - 3.0);
            }
        }
    }
}

extern "C" void kernel_launch(void* const* d_in, const int* in_sizes, int n_in,
                              void* d_out, int out_size, void* d_ws, size_t ws_size,
                              hipStream_t stream) {
    const float* data = (const float*)d_in[0];
    const float* W    = (const float*)d_in[1];
    const float* bias = (const float*)d_in[2];
    const int*   aidx = (const int*)d_in[3];
    float* out = (float*)d_out;

    char* ws = (char*)d_ws;
    unsigned* ticket = (unsigned*)(ws + 0);
    double*   absP   = (double*)  (ws + 1024);
    float*    maxP   = (float*)   (ws + 10752);
    float*    stats  = (float*)   (ws + 15616);
    double*   sP     = (double*)  (ws + 16384);
    float*    ch     = (float*)   (ws + 65536);

    hipMemsetAsync(ticket, 0, 16, stream);

    dim3 grid(NBX, BATCH);
    conv_stats<<<grid, dim3(TPB), 0, stream>>>(data, W, bias, aidx, ch,
                                               absP, maxP, stats, ticket);
    softmax_pass<<<grid, dim3(TPB), 0, stream>>>(ch, stats, out + 2 * BATCH, sP,
                                                 out, ticket + 1);
}